// Round 7
// baseline (140.808 us; speedup 1.0000x reference)
//
#include <hip/hip_runtime.h>

#define N 64
#define MARGIN 0.1f
#define WAVES_PER_BLOCK 4
#define NBLOCKS 2048
#define ROWS_PER_WAVE 4   // 2048 blk * 4 waves * 4 rows = 32768

// closed form (verified R2/R4/R5/R6, absmax 0.0): row_loss = sum_e u_e*(q_e-p_e)
//   p_e = #{k: lab_k < lab_e},  u_e = sc_e - MARGIN*p_e,  q_e = #{k: u_k < u_e}
//
// R7: pipe-split supply. Pass-1 broadcasts on SMEM (s_load_dwordx4 of labels),
// pass-2 broadcasts on LDS (1 ds_write + 16 uniform ds_read_b128 -- no
// v_readlane on the VALU), next row's per-lane loads prefetched on VMEM.
// VALU does only cmp/add/fma (~280 inst/row vs ~470 in R6).
__global__ __launch_bounds__(256, 8) void mmrl_partial(const float* __restrict__ scores,
                                                       const float* __restrict__ labels,
                                                       float* __restrict__ partial,
                                                       int rows) {
    __shared__ float ubuf[WAVES_PER_BLOCK][N];
    __shared__ float wsum[WAVES_PER_BLOCK];

    const int lane = threadIdx.x & 63;
    const int w    = threadIdx.x >> 6;
    const int gwave = blockIdx.x * WAVES_PER_BLOCK + w;
    const int nwaves = NBLOCKS * WAVES_PER_BLOCK;

    float acc = 0.0f;
    int row = gwave;
    float labv = (row < rows) ? labels[row * N + lane] : 0.0f;
    float scv  = (row < rows) ? scores[row * N + lane] : 0.0f;

    #pragma unroll
    for (int it = 0; it < ROWS_PER_WAVE; ++it) {
        // ---- prefetch next row (VMEM, overlaps this row's compute) ----
        const int nrow = row + nwaves;
        float nl = 0.0f, ns = 0.0f;
        if (it + 1 < ROWS_PER_WAVE && nrow < rows) {
            nl = labels[nrow * N + lane];
            ns = scores[nrow * N + lane];
        }

        const int base = __builtin_amdgcn_readfirstlane(row) * N;

        // ---- pass 1: label rank p (SMEM float4 broadcasts) ----
        const float4* L4 = (const float4*)(labels + base);
        int p0 = 0, p1 = 0, p2 = 0, p3 = 0;
        #pragma unroll
        for (int kk = 0; kk < N / 4; ++kk) {
            const float4 a = L4[kk];
            p0 += (a.x < labv);
            p1 += (a.y < labv);
            p2 += (a.z < labv);
            p3 += (a.w < labv);
        }
        const int pv = (p0 + p1) + (p2 + p3);

        const float u = fmaf(-MARGIN, (float)pv, scv);

        // ---- pass 2: u rank q (LDS float4 broadcasts; no readlane) ----
        ubuf[w][lane] = u;
        asm volatile("s_waitcnt lgkmcnt(0)" ::: "memory");  // intra-wave, in-order LDS
        const float4* U4 = (const float4*)ubuf[w];
        int q0 = 0, q1 = 0, q2 = 0, q3 = 0;
        #pragma unroll
        for (int kk = 0; kk < N / 4; ++kk) {
            const float4 a = U4[kk];
            q0 += (a.x < u);
            q1 += (a.y < u);
            q2 += (a.z < u);
            q3 += (a.w < u);
        }
        const int qv = (q0 + q1) + (q2 + q3);

        const float c = fmaf(u, (float)(qv - pv), 0.0f);
        acc += (row < rows) ? c : 0.0f;

        labv = nl; scv = ns; row = nrow;
    }

    // ---- wave reduction ----
    #pragma unroll
    for (int off = 32; off > 0; off >>= 1)
        acc += __shfl_down(acc, off, 64);

    if (lane == 0) wsum[w] = acc;
    __syncthreads();
    if (threadIdx.x == 0) {
        float s = 0.0f;
        #pragma unroll
        for (int i = 0; i < WAVES_PER_BLOCK; ++i) s += wsum[i];
        partial[blockIdx.x] = s;          // plain store, no atomic
    }
}

__global__ __launch_bounds__(256) void mmrl_reduce(const float* __restrict__ partial,
                                                   float* __restrict__ out,
                                                   int npartial, float inv_rows) {
    const int t = threadIdx.x;
    float s = 0.0f;
    for (int i = t; i < npartial; i += 256)
        s += partial[i];
    #pragma unroll
    for (int off = 32; off > 0; off >>= 1)
        s += __shfl_down(s, off, 64);
    __shared__ float wsum[4];
    if ((t & 63) == 0) wsum[t >> 6] = s;
    __syncthreads();
    if (t == 0)
        out[0] = (wsum[0] + wsum[1] + wsum[2] + wsum[3]) * inv_rows;
}

extern "C" void kernel_launch(void* const* d_in, const int* in_sizes, int n_in,
                              void* d_out, int out_size, void* d_ws, size_t ws_size,
                              hipStream_t stream) {
    const float* scores = (const float*)d_in[0];
    const float* labels = (const float*)d_in[1];
    float* out = (float*)d_out;
    float* partial = (float*)d_ws;        // 2048 floats = 8 KB << ws_size
    const int rows = in_sizes[0] / N;     // 32768

    mmrl_partial<<<NBLOCKS, 256, 0, stream>>>(scores, labels, partial, rows);
    mmrl_reduce<<<1, 256, 0, stream>>>(partial, out, NBLOCKS, 1.0f / (float)rows);
}

// Round 8
// 84.337 us; speedup vs baseline: 1.6696x; 1.6696x over previous
//
#include <hip/hip_runtime.h>

#define N 64
#define MARGIN 0.1f
#define WAVES_PER_BLOCK 4
#define NBLOCKS 2048

// closed form (verified R2..R7, absmax 0.0): row_loss = sum_e u_e*(q_e - p_e)
//   p_e = #{k: lab_k < lab_e},  u_e = sc_e - MARGIN*p_e,  q_e = #{k: u_k < u_e}
//
// R8: R7's pipe-split supply WITHOUT the pressure sources that made R7 spill
// (172 MB scratch writes under launch_bounds(256,8) + 4-row unrolled
// pipeline). Pass-1 broadcasts: SMEM s_load_dwordx4. Pass-2 broadcasts:
// LDS uniform ds_read_b128 (no v_readlane on the VALU). One row per
// grid-stride iteration; no min-waves cap; compiler free on VGPRs.
__global__ __launch_bounds__(256) void mmrl_partial(const float* __restrict__ scores,
                                                    const float* __restrict__ labels,
                                                    float* __restrict__ partial,
                                                    int rows) {
    __shared__ float ubuf[WAVES_PER_BLOCK][N];
    __shared__ float wsum[WAVES_PER_BLOCK];

    const int lane = threadIdx.x & 63;
    const int w    = threadIdx.x >> 6;
    const int gwave = blockIdx.x * WAVES_PER_BLOCK + w;
    const int nwaves = NBLOCKS * WAVES_PER_BLOCK;

    float acc = 0.0f;

    for (int row = gwave; row < rows; row += nwaves) {
        const int base = __builtin_amdgcn_readfirstlane(row) * N;
        const float labv = labels[base + lane];   // coalesced per-lane copy
        const float scv  = scores[base + lane];

        // ---- pass 1: label rank p (SMEM float4 broadcasts) ----
        const float4* L4 = (const float4*)(labels + base);
        int p0 = 0, p1 = 0, p2 = 0, p3 = 0;       // 4 independent carry chains
        #pragma unroll
        for (int kk = 0; kk < N / 4; ++kk) {
            const float4 a = L4[kk];
            p0 += (a.x < labv);
            p1 += (a.y < labv);
            p2 += (a.z < labv);
            p3 += (a.w < labv);
        }
        const int pv = (p0 + p1) + (p2 + p3);

        const float u = fmaf(-MARGIN, (float)pv, scv);

        // ---- pass 2: u rank q (LDS uniform float4 broadcasts) ----
        ubuf[w][lane] = u;
        asm volatile("s_waitcnt lgkmcnt(0)" ::: "memory");  // intra-wave LDS in-order
        const float4* U4 = (const float4*)ubuf[w];
        int q0 = 0, q1 = 0, q2 = 0, q3 = 0;
        #pragma unroll
        for (int kk = 0; kk < N / 4; ++kk) {
            const float4 a = U4[kk];
            q0 += (a.x < u);
            q1 += (a.y < u);
            q2 += (a.z < u);
            q3 += (a.w < u);
        }
        const int qv = (q0 + q1) + (q2 + q3);

        acc = fmaf(u, (float)(qv - pv), acc);
    }

    // ---- wave reduction ----
    #pragma unroll
    for (int off = 32; off > 0; off >>= 1)
        acc += __shfl_down(acc, off, 64);

    if (lane == 0) wsum[w] = acc;
    __syncthreads();
    if (threadIdx.x == 0) {
        float s = 0.0f;
        #pragma unroll
        for (int i = 0; i < WAVES_PER_BLOCK; ++i) s += wsum[i];
        partial[blockIdx.x] = s;          // plain store, no atomic
    }
}

__global__ __launch_bounds__(256) void mmrl_reduce(const float* __restrict__ partial,
                                                   float* __restrict__ out,
                                                   int npartial, float inv_rows) {
    const int t = threadIdx.x;
    float s = 0.0f;
    for (int i = t; i < npartial; i += 256)
        s += partial[i];
    #pragma unroll
    for (int off = 32; off > 0; off >>= 1)
        s += __shfl_down(s, off, 64);
    __shared__ float wsum[4];
    if ((t & 63) == 0) wsum[t >> 6] = s;
    __syncthreads();
    if (t == 0)
        out[0] = (wsum[0] + wsum[1] + wsum[2] + wsum[3]) * inv_rows;
}

extern "C" void kernel_launch(void* const* d_in, const int* in_sizes, int n_in,
                              void* d_out, int out_size, void* d_ws, size_t ws_size,
                              hipStream_t stream) {
    const float* scores = (const float*)d_in[0];
    const float* labels = (const float*)d_in[1];
    float* out = (float*)d_out;
    float* partial = (float*)d_ws;        // 2048 floats = 8 KB << ws_size
    const int rows = in_sizes[0] / N;     // 32768

    mmrl_partial<<<NBLOCKS, 256, 0, stream>>>(scores, labels, partial, rows);
    mmrl_reduce<<<1, 256, 0, stream>>>(partial, out, NBLOCKS, 1.0f / (float)rows);
}